// Round 1
// baseline (1313.787 us; speedup 1.0000x reference)
//
#include <hip/hip_runtime.h>
#include <math.h>

#define BB   2
#define CC   256
#define NPT  4096
#define HH   4
#define DD   64
#define KNN  16
#define EPSBN 1e-5f

// ---------------- prep: fold rp BN into w1, reduce rp_w2 over heads ----------------
__global__ __launch_bounds__(256)
void prep_kernel(const float* __restrict__ rp_w1, const float* __restrict__ rp_g,
                 const float* __restrict__ rp_b,  const float* __restrict__ rp_m,
                 const float* __restrict__ rp_v,  const float* __restrict__ rp_w2,
                 float4* __restrict__ w1f, float4* __restrict__ W2t) {
  int c = threadIdx.x;
  float s  = rp_g[c] / sqrtf(rp_v[c] + EPSBN);
  float b0 = rp_b[c] - rp_m[c] * s;
  w1f[c] = make_float4(rp_w1[c*3+0]*s, rp_w1[c*3+1]*s, rp_w1[c*3+2]*s, b0);
  float a0=0.f,a1=0.f,a2=0.f,a3=0.f;
  for (int o = 0; o < 64; o++) {
    a0 += rp_w2[(      o)*CC + c];
    a1 += rp_w2[( 64 + o)*CC + c];
    a2 += rp_w2[(128 + o)*CC + c];
    a3 += rp_w2[(192 + o)*CC + c];
  }
  W2t[c] = make_float4(a0,a1,a2,a3);
}

// ---------------- KNN: block = 64 queries x 4 candidate slices ----------------
__global__ __launch_bounds__(256)
void knn_kernel(const float* __restrict__ xyz, int* __restrict__ idx_out) {
  __shared__ float smem[3*NPT];   // 48KB points; reused as merge buffer
  int blk   = blockIdx.x;
  int b     = blk >> 6;            // 64 blocks per batch
  int qbase = (blk & 63) * 64;
  float* px = smem; float* py = smem + NPT; float* pz = smem + 2*NPT;
  const float* base = xyz + (size_t)b * 3 * NPT;
  for (int i = threadIdx.x; i < NPT; i += 256) {
    px[i] = base[i]; py[i] = base[NPT + i]; pz[i] = base[2*NPT + i];
  }
  __syncthreads();
  int wv = threadIdx.x >> 6;
  int lane = threadIdx.x & 63;
  int qn = qbase + lane;
  float qx = px[qn], qy = py[qn], qz = pz[qn];
  float qsq = qx*qx + qy*qy + qz*qz;
  float bd[16]; int bi[16];
#pragma unroll
  for (int t = 0; t < 16; t++) { bd[t] = 3.4e38f; bi[t] = 0x7fffffff; }
  float worst = 3.4e38f; int wslot = 0; int widx = 0x7fffffff;
  int mstart = wv * (NPT/4);
  for (int m = mstart; m < mstart + NPT/4; m++) {
    float mx = px[m], my = py[m], mz = pz[m];
    float msq = mx*mx + my*my + mz*mz;
    float dt  = qx*mx + qy*my + qz*mz;
    float dist = qsq + msq - 2.0f*dt;
    if (dist < worst) {               // strict <: ascending scan keeps lower idx on ties
      bd[wslot] = dist; bi[wslot] = m;
      worst = -3.4e38f; widx = -1;
#pragma unroll
      for (int t = 0; t < 16; t++) {
        bool better = (bd[t] > worst) || (bd[t] == worst && bi[t] > widx);
        if (better) { worst = bd[t]; widx = bi[t]; wslot = t; }
      }
    }
  }
  __syncthreads();                    // everyone done reading px/py/pz
  float* md = smem;                   // [4][64][16] dists
  int*   mi = (int*)(smem + 4096);    // [4][64][16] indices
#pragma unroll
  for (int t = 0; t < 16; t++) {
    md[(wv*64 + lane)*16 + t] = bd[t];
    mi[(wv*64 + lane)*16 + t] = bi[t];
  }
  __syncthreads();
  if (threadIdx.x < 64) {
    int q = threadIdx.x;
    int ob = ((b * NPT) + qbase + q) * 16;
    for (int sel = 0; sel < 16; sel++) {
      float bestd = 3.5e38f; int besti = 0x7fffffff; int bw = 0, bt = 0;
      for (int w = 0; w < 4; w++) {
#pragma unroll
        for (int t = 0; t < 16; t++) {
          float d0 = md[(w*64 + q)*16 + t];
          int   i0 = mi[(w*64 + q)*16 + t];
          if (d0 < bestd || (d0 == bestd && i0 < besti)) { bestd=d0; besti=i0; bw=w; bt=t; }
        }
      }
      md[(bw*64 + q)*16 + bt] = 3.4e38f;
      mi[(bw*64 + q)*16 + bt] = 0x7fffffff;
      idx_out[ob + sel] = besti;
    }
  }
}

// ---------------- fused rel-pos bias: one thread per (b,n,k) ----------------
__global__ __launch_bounds__(256)
void bias_kernel(const float* __restrict__ xyz, const int* __restrict__ idx,
                 const float4* __restrict__ w1f, const float4* __restrict__ W2t,
                 float4* __restrict__ biasB) {
  __shared__ float4 sw1[256];
  __shared__ float4 sw2[256];
  int tid = threadIdx.x;
  sw1[tid] = w1f[tid];
  sw2[tid] = W2t[tid];
  __syncthreads();
  int gid = blockIdx.x * 256 + tid;      // (b*N + n)*K + k
  int b = gid >> 16;
  int n = (gid >> 4) & 4095;
  int j = idx[gid];
  const float* base = xyz + (size_t)b * 3 * NPT;
  float rx = base[j]         - base[n];
  float ry = base[NPT + j]   - base[NPT + n];
  float rz = base[2*NPT + j] - base[2*NPT + n];
  float a0=0.f,a1=0.f,a2=0.f,a3=0.f;
#pragma unroll 8
  for (int c = 0; c < 256; c++) {
    float4 w = sw1[c];
    float t = fmaf(rx, w.x, fmaf(ry, w.y, fmaf(rz, w.z, w.w)));
    t = fmaxf(t, 0.f);
    float4 w2 = sw2[c];
    a0 = fmaf(t, w2.x, a0); a1 = fmaf(t, w2.y, a1);
    a2 = fmaf(t, w2.z, a2); a3 = fmaf(t, w2.w, a3);
  }
  biasB[gid] = make_float4(a0,a1,a2,a3);
}

// ---------------- fused attention: block per (b,n); wave = head, lane = d ----------------
__global__ __launch_bounds__(256)
void attn_kernel(const float* __restrict__ q_t, const float* __restrict__ kv_t,
                 const float* __restrict__ biasB, const int* __restrict__ idx,
                 float* __restrict__ attn_t) {
  int bn = blockIdx.x;
  int b  = bn >> 12;
  __shared__ int sidx[16];
  if (threadIdx.x < 16) sidx[threadIdx.x] = idx[bn*16 + threadIdx.x];
  __syncthreads();
  int wv = threadIdx.x >> 6;
  int c  = threadIdx.x;                          // = head*64 + d
  float qv = q_t[(size_t)bn*256 + c] * 0.125f;   // scale = d^-0.5
  size_t kvbase = (size_t)b * NPT * 512;
  float part[16];
#pragma unroll
  for (int k = 0; k < 16; k++) {
    int j = sidx[k];
    part[k] = qv * kv_t[kvbase + (size_t)j*512 + c];
  }
#pragma unroll
  for (int off = 32; off > 0; off >>= 1) {
#pragma unroll
    for (int k = 0; k < 16; k++) part[k] += __shfl_xor(part[k], off, 64);
  }
  float mx = -3.4e38f;
#pragma unroll
  for (int k = 0; k < 16; k++) {
    part[k] += biasB[(size_t)(bn*16 + k)*4 + wv];
    mx = fmaxf(mx, part[k]);
  }
  float s = 0.f;
#pragma unroll
  for (int k = 0; k < 16; k++) { part[k] = __expf(part[k] - mx); s += part[k]; }
  float inv = 1.f / s;
  float o = 0.f;
#pragma unroll
  for (int k = 0; k < 16; k++) {
    int j = sidx[k];
    o = fmaf(part[k], kv_t[kvbase + (size_t)j*512 + 256 + c], o);
  }
  attn_t[(size_t)bn*256 + c] = o * inv;
}

// ---------------- tiled SGEMM, 128m x 64n tile, 8x4 per thread ----------------
// BL=0: Bm is [Kd, N] (channel-major x);  BL=1: Bm is [N, Kd] (point-major)
// EPI: 0 plain -> Out[B][N][M];  1 +bias,relu -> Out[B][N][M]
//      2 +resid x[B][C][N], BN1 -> Out[B][N][M];  3 +bias,+resid[B][N][M], BN2 -> Out[B][M][N]
struct GemmP {
  const float* W; const float* Bm; float* Out;
  int M; int Kd;
  const float* bias; const float* resid;
  const float* bng; const float* bnb; const float* bnm; const float* bnv;
};

template<int BL, int EPI>
__global__ __launch_bounds__(256)
void gemm_kernel(GemmP p) {
  __shared__ float Ws[32][128];
  __shared__ float Xs[32][64];
  const int tid = threadIdx.x;
  const int b  = blockIdx.z;
  const int m0 = blockIdx.y * 128;
  const int n0 = blockIdx.x * 64;
  const float* Bp = p.Bm + (size_t)b * p.Kd * NPT;
  float acc[8][4];
#pragma unroll
  for (int i = 0; i < 8; i++)
#pragma unroll
    for (int j = 0; j < 4; j++) acc[i][j] = 0.f;
  const int tm = (tid & 15) * 4;
  const int tn = (tid >> 4) * 4;
  const int nch = p.Kd >> 5;
  for (int kc = 0; kc < nch; kc++) {
    const int c0 = kc * 32;
    {
      int wr = tid >> 3;
      int wc = (tid & 7) * 4;
#pragma unroll
      for (int it = 0; it < 4; it++) {
        int m = wr + it*32;
        float4 w4 = *(const float4*)(p.W + (size_t)(m0 + m)*p.Kd + c0 + wc);
        Ws[wc+0][m] = w4.x; Ws[wc+1][m] = w4.y; Ws[wc+2][m] = w4.z; Ws[wc+3][m] = w4.w;
      }
    }
    if (BL == 0) {
      int xr = tid >> 4;
      int xc = (tid & 15) * 4;
#pragma unroll
      for (int it = 0; it < 2; it++) {
        int c = xr + it*16;
        float4 v = *(const float4*)(Bp + (size_t)(c0 + c)*NPT + n0 + xc);
        Xs[c][xc+0] = v.x; Xs[c][xc+1] = v.y; Xs[c][xc+2] = v.z; Xs[c][xc+3] = v.w;
      }
    } else {
      int xr = tid >> 3;
      int xc = (tid & 7) * 4;
#pragma unroll
      for (int it = 0; it < 2; it++) {
        int n = xr + it*32;
        float4 v = *(const float4*)(Bp + (size_t)(n0 + n)*p.Kd + c0 + xc);
        Xs[xc+0][n] = v.x; Xs[xc+1][n] = v.y; Xs[xc+2][n] = v.z; Xs[xc+3][n] = v.w;
      }
    }
    __syncthreads();
#pragma unroll
    for (int kk = 0; kk < 32; kk++) {
      float4 a0 = *(const float4*)&Ws[kk][tm];
      float4 a1 = *(const float4*)&Ws[kk][tm + 64];
      float4 bv = *(const float4*)&Xs[kk][tn];
      float am[8] = {a0.x,a0.y,a0.z,a0.w,a1.x,a1.y,a1.z,a1.w};
      float bn_[4] = {bv.x,bv.y,bv.z,bv.w};
#pragma unroll
      for (int i = 0; i < 8; i++)
#pragma unroll
        for (int j = 0; j < 4; j++)
          acc[i][j] = fmaf(am[i], bn_[j], acc[i][j]);
    }
    __syncthreads();
  }
  const int gn = n0 + tn;
  if (EPI == 0 || EPI == 1) {
    float bs[8];
#pragma unroll
    for (int g = 0; g < 2; g++)
#pragma unroll
      for (int i = 0; i < 4; i++)
        bs[g*4+i] = (EPI == 1) ? p.bias[m0 + g*64 + tm + i] : 0.f;
#pragma unroll
    for (int j = 0; j < 4; j++) {
      size_t row = ((size_t)b*NPT + gn + j) * p.M + m0;
      float v[8];
#pragma unroll
      for (int i = 0; i < 8; i++) {
        float t = acc[i][j] + bs[i];
        v[i] = (EPI == 1) ? fmaxf(t, 0.f) : t;
      }
      *(float4*)(p.Out + row + tm)      = make_float4(v[0],v[1],v[2],v[3]);
      *(float4*)(p.Out + row + 64 + tm) = make_float4(v[4],v[5],v[6],v[7]);
    }
  } else if (EPI == 2) {
    float sc[8], sh[8], r[8][4];
#pragma unroll
    for (int g = 0; g < 2; g++)
#pragma unroll
      for (int i = 0; i < 4; i++) {
        int m = m0 + g*64 + tm + i;
        float s = p.bng[m] / sqrtf(p.bnv[m] + EPSBN);
        sc[g*4+i] = s; sh[g*4+i] = p.bnb[m] - p.bnm[m]*s;
        float4 xr = *(const float4*)(p.resid + ((size_t)b*CC + m)*NPT + gn);
        r[g*4+i][0]=xr.x; r[g*4+i][1]=xr.y; r[g*4+i][2]=xr.z; r[g*4+i][3]=xr.w;
      }
#pragma unroll
    for (int j = 0; j < 4; j++) {
      size_t row = ((size_t)b*NPT + gn + j) * p.M + m0;
      float v[8];
#pragma unroll
      for (int i = 0; i < 8; i++) v[i] = (acc[i][j] + r[i][j]) * sc[i] + sh[i];
      *(float4*)(p.Out + row + tm)      = make_float4(v[0],v[1],v[2],v[3]);
      *(float4*)(p.Out + row + 64 + tm) = make_float4(v[4],v[5],v[6],v[7]);
    }
  } else {  // EPI == 3 : final out [B][M][N]
    float sc[8], sh[8], bs[8], val[8][4];
#pragma unroll
    for (int g = 0; g < 2; g++)
#pragma unroll
      for (int i = 0; i < 4; i++) {
        int m = m0 + g*64 + tm + i;
        float s = p.bng[m] / sqrtf(p.bnv[m] + EPSBN);
        sc[g*4+i] = s; sh[g*4+i] = p.bnb[m] - p.bnm[m]*s;
        bs[g*4+i] = p.bias[m];
      }
#pragma unroll
    for (int j = 0; j < 4; j++) {
      size_t rrow = ((size_t)b*NPT + gn + j) * p.M + m0;
      float4 r0 = *(const float4*)(p.resid + rrow + tm);
      float4 r1 = *(const float4*)(p.resid + rrow + 64 + tm);
      float rr[8] = {r0.x,r0.y,r0.z,r0.w,r1.x,r1.y,r1.z,r1.w};
#pragma unroll
      for (int i = 0; i < 8; i++)
        val[i][j] = (acc[i][j] + bs[i] + rr[i]) * sc[i] + sh[i];
    }
#pragma unroll
    for (int g = 0; g < 2; g++)
#pragma unroll
      for (int i = 0; i < 4; i++) {
        int m = m0 + g*64 + tm + i;
        *(float4*)(p.Out + ((size_t)b*p.M + m)*NPT + gn) =
            make_float4(val[g*4+i][0], val[g*4+i][1], val[g*4+i][2], val[g*4+i][3]);
      }
  }
}

extern "C" void kernel_launch(void* const* d_in, const int* in_sizes, int n_in,
                              void* d_out, int out_size, void* d_ws, size_t ws_size,
                              hipStream_t stream) {
  const float* x     = (const float*)d_in[0];
  const float* xyz   = (const float*)d_in[1];
  const float* Wq    = (const float*)d_in[2];
  const float* Wkv   = (const float*)d_in[3];
  const float* Wproj = (const float*)d_in[4];
  const float* rp_w1 = (const float*)d_in[5];
  const float* rp_g  = (const float*)d_in[6];
  const float* rp_b  = (const float*)d_in[7];
  const float* rp_m  = (const float*)d_in[8];
  const float* rp_v  = (const float*)d_in[9];
  const float* rp_w2 = (const float*)d_in[10];
  const float* bn1_g = (const float*)d_in[11];
  const float* bn1_b = (const float*)d_in[12];
  const float* bn1_m = (const float*)d_in[13];
  const float* bn1_v = (const float*)d_in[14];
  const float* bn2_g = (const float*)d_in[15];
  const float* bn2_b = (const float*)d_in[16];
  const float* bn2_m = (const float*)d_in[17];
  const float* bn2_v = (const float*)d_in[18];
  const float* ffn_w1 = (const float*)d_in[19];
  const float* ffn_b1 = (const float*)d_in[20];
  const float* ffn_w2 = (const float*)d_in[21];
  const float* ffn_b2 = (const float*)d_in[22];

  char* ws = (char*)d_ws;
  float4* w1f   = (float4*)(ws + 0);                       //   4 KB
  float4* W2t   = (float4*)(ws + 4096);                    //   4 KB
  int*    idx   = (int*)  (ws + 8192);                     // 512 KB
  float*  q_t   = (float*)(ws + 532480);                   //   8 MB [B,N,256]
  float*  kv_t  = (float*)(ws + 8921088);                  //  16 MB [B,N,512]
  float*  biasB = (float*)(ws + 25698304);                 //   2 MB [B,N,K,H]
  float*  attn_t= (float*)(ws + 27795456);                 //   8 MB [B,N,256]
  float*  x1_t  = (float*)(ws + 36184064);                 //   8 MB [B,N,256]
  float*  h_t   = (float*)(ws + 532480);                   //  32 MB, reuses q/kv/bias/attn region (dead by then)

  prep_kernel<<<1, 256, 0, stream>>>(rp_w1, rp_g, rp_b, rp_m, rp_v, rp_w2, w1f, W2t);
  knn_kernel<<<BB*(NPT/64), 256, 0, stream>>>(xyz, idx);

  GemmP pq  = {Wq,  x, q_t,  256, 256, nullptr, nullptr, nullptr, nullptr, nullptr, nullptr};
  gemm_kernel<0,0><<<dim3(64,2,2), 256, 0, stream>>>(pq);
  GemmP pkv = {Wkv, x, kv_t, 512, 256, nullptr, nullptr, nullptr, nullptr, nullptr, nullptr};
  gemm_kernel<0,0><<<dim3(64,4,2), 256, 0, stream>>>(pkv);

  bias_kernel<<<(BB*NPT*KNN)/256, 256, 0, stream>>>(xyz, idx, w1f, W2t, (float4*)biasB);
  attn_kernel<<<BB*NPT, 256, 0, stream>>>(q_t, kv_t, biasB, idx, attn_t);

  GemmP pp = {Wproj, attn_t, x1_t, 256, 256, nullptr, x, bn1_g, bn1_b, bn1_m, bn1_v};
  gemm_kernel<1,2><<<dim3(64,2,2), 256, 0, stream>>>(pp);
  GemmP p1 = {ffn_w1, x1_t, h_t, 1024, 256, ffn_b1, nullptr, nullptr, nullptr, nullptr, nullptr};
  gemm_kernel<1,1><<<dim3(64,8,2), 256, 0, stream>>>(p1);
  GemmP p2 = {ffn_w2, h_t, (float*)d_out, 256, 1024, ffn_b2, x1_t, bn2_g, bn2_b, bn2_m, bn2_v};
  gemm_kernel<1,3><<<dim3(64,2,2), 256, 0, stream>>>(p2);
}